// Round 1
// 322.458 us; speedup vs baseline: 1.0027x; 1.0027x over previous
//
#include <hip/hip_runtime.h>
#include <cstdint>

// YOLO head decode: [B, 3*86, 76, 76] fp32 -> [B, 3*76*76, 86] fp32
// c0: (sig(v)+i)*8, c1: (sig(v)+j)*8, c2: exp(v)*aw, c3: exp(v)*ah, c>=4: sig(v)
// (anchor/stride * stride cancels -> raw anchors)
//
// v2: transform moved to the LOAD phase (channel is thread-uniform there, so the
// c<4 branch touches only 32 threads/block), LDS tile stored in OUTPUT layout
// [s][c] unpadded. Store phase is a pure linear copy: lane-consecutive
// ds_read_b128 (conflict-free) -> nontemporal global dwordx4. This removes the
// old 8-way LDS bank conflict on the scalar gather (stride-4-float lane
// pattern), the per-element divergence, and the magic-div/wrap bookkeeping.

#define GDIM 76
#define SP   (GDIM * GDIM)   // 5776
#define NCH  86
#define NANC 3
#define TS   64              // spatial positions per tile
#define NV   (NCH * TS / 4)  // 1376 float4 per full tile

typedef float v4f __attribute__((ext_vector_type(4)));

__global__ __launch_bounds__(256) void yolo_decode_kernel(
    const float* __restrict__ in, float* __restrict__ out) {
    // Output-layout staging: tile[s][c], unpadded & contiguous — byte-identical
    // to this block's output region. 22016 B -> 7 blocks/CU (28 waves/CU).
    __shared__ __align__(16) float tile[TS * NCH];

    const int tid   = threadIdx.x;
    const int chunk = blockIdx.x;        // 0..90
    const int a     = blockIdx.y;        // 0..2
    const int b     = blockIdx.z;        // 0..B-1
    const int s0    = chunk * TS;
    const int valid = min(TS, SP - s0);  // 64, or 16 tail (mult of 4)

    const float aw = (a == 0) ? 116.0f : (a == 1) ? 156.0f : 373.0f;
    const float ah = (a == 0) ?  90.0f : (a == 1) ? 198.0f : 326.0f;

    const float* inp = in + ((size_t)(b * (NANC * NCH) + a * NCH)) * SP + s0;

    // ---- phase 1a: issue all global loads (independent, coalesced float4) ----
    v4f vbuf[6];
    #pragma unroll
    for (int k = 0; k < 6; ++k) {
        const int idx = tid + (k << 8);
        const int c   = idx >> 4;
        const int s4  = (idx & 15) << 2;
        if (idx < NV && s4 < valid)
            vbuf[k] = *(const v4f*)(inp + (size_t)c * SP + s4);
    }

    // ---- phase 1b: transform (thread-uniform channel) + scatter to LDS ----
    #pragma unroll
    for (int k = 0; k < 6; ++k) {
        const int idx = tid + (k << 8);
        const int c   = idx >> 4;
        const int s4  = (idx & 15) << 2;
        if (idx < NV && s4 < valid) {
            v4f v = vbuf[k];
            if (c >= 4) {
                #pragma unroll
                for (int j = 0; j < 4; ++j)
                    v[j] = __builtin_amdgcn_rcpf(1.0f + __expf(-v[j]));  // sigmoid
            } else if (c == 0) {
                const int sp_ = s0 + s4;
                #pragma unroll
                for (int j = 0; j < 4; ++j) {
                    const float sg = __builtin_amdgcn_rcpf(1.0f + __expf(-v[j]));
                    v[j] = (sg + (float)((sp_ + j) % GDIM)) * 8.0f;
                }
            } else if (c == 1) {
                const int sp_ = s0 + s4;
                #pragma unroll
                for (int j = 0; j < 4; ++j) {
                    const float sg = __builtin_amdgcn_rcpf(1.0f + __expf(-v[j]));
                    v[j] = (sg + (float)((sp_ + j) / GDIM)) * 8.0f;
                }
            } else {  // c == 2 or 3
                const float an = (c == 2) ? aw : ah;
                #pragma unroll
                for (int j = 0; j < 4; ++j)
                    v[j] = __expf(v[j]) * an;
            }
            // scatter: addr stride 86 floats -> 4-way bank aliasing only (cheap)
            #pragma unroll
            for (int j = 0; j < 4; ++j)
                tile[(s4 + j) * NCH + c] = v[j];
        }
    }
    __syncthreads();

    // ---- phase 2: pure copy, LDS (linear b128, conflict-free) -> global NT ----
    v4f* outp = (v4f*)(out + ((size_t)b * (NANC * SP) + (size_t)a * SP + (size_t)s0) * NCH);
    const int nvalid = (valid * NCH) >> 2;   // 1376 or 344
    const v4f* lv = (const v4f*)tile;
    #pragma unroll
    for (int k = 0; k < 6; ++k) {
        const int v = tid + (k << 8);
        if (v < nvalid)
            __builtin_nontemporal_store(lv[v], outp + v);
    }
}

extern "C" void kernel_launch(void* const* d_in, const int* in_sizes, int n_in,
                              void* d_out, int out_size, void* d_ws, size_t ws_size,
                              hipStream_t stream) {
    const float* in = (const float*)d_in[0];
    float* out = (float*)d_out;
    const int B = in_sizes[0] / (NANC * NCH * SP);   // 32
    dim3 grid((SP + TS - 1) / TS, NANC, B);          // (91, 3, 32)
    yolo_decode_kernel<<<grid, 256, 0, stream>>>(in, out);
}

// Round 2
// 322.162 us; speedup vs baseline: 1.0036x; 1.0009x over previous
//
#include <hip/hip_runtime.h>
#include <cstdint>

// YOLO head decode: [B, 3*86, 76, 76] fp32 -> [B, 3*76*76, 86] fp32
// c0: (sig(v)+i)*8, c1: (sig(v)+j)*8, c2: exp(v)*aw, c3: exp(v)*ah, c>=4: sig(v)
// (anchor/stride * stride cancels -> raw anchors)
//
// v3: TS 64->128, block 256->512. Theory: v1 and v2 (different compute/LDS
// structures) both sat at ~116 us -> bottleneck is the global READ pattern
// (256B segments at 23KB stride = DRAM page scatter). TS=128 doubles each
// contiguous channel segment to 512B. LDS = 44KB -> 3 blocks/CU (24 waves).
// Transform still happens at load time (channel is uniform per 32-lane group),
// LDS tile is in output layout, store phase is a pure linear copy.

#define GDIM 76
#define SP   (GDIM * GDIM)   // 5776
#define NCH  86
#define NANC 3
#define TS   128             // spatial positions per tile
#define NT_  512             // threads per block
#define NV   (NCH * TS / 4)  // 2752 float4 per full tile
#define F4PC (TS / 4)        // 32 float4 per channel

typedef float v4f __attribute__((ext_vector_type(4)));

__global__ __launch_bounds__(NT_) void yolo_decode_kernel(
    const float* __restrict__ in, float* __restrict__ out) {
    // Output-layout staging: tile[s][c], unpadded & contiguous — byte-identical
    // to this block's output region. 44032 B -> 3 blocks/CU.
    __shared__ __align__(16) float tile[TS * NCH];

    const int tid   = threadIdx.x;
    const int chunk = blockIdx.x;        // 0..45
    const int a     = blockIdx.y;        // 0..2
    const int b     = blockIdx.z;        // 0..B-1
    const int s0    = chunk * TS;
    const int valid = min(TS, SP - s0);  // 128, or 16 tail (mult of 4)

    const float aw = (a == 0) ? 116.0f : (a == 1) ? 156.0f : 373.0f;
    const float ah = (a == 0) ?  90.0f : (a == 1) ? 198.0f : 326.0f;

    const float* inp = in + ((size_t)(b * (NANC * NCH) + a * NCH)) * SP + s0;

    // ---- phase 1a: issue all global loads (independent, coalesced float4) ----
    v4f vbuf[6];
    #pragma unroll
    for (int k = 0; k < 6; ++k) {
        const int idx = tid + k * NT_;
        const int c   = idx / F4PC;          // idx >> 5
        const int s4  = (idx % F4PC) << 2;
        if (idx < NV && s4 < valid)
            vbuf[k] = *(const v4f*)(inp + (size_t)c * SP + s4);
    }

    // ---- phase 1b: transform (thread-uniform channel) + scatter to LDS ----
    #pragma unroll
    for (int k = 0; k < 6; ++k) {
        const int idx = tid + k * NT_;
        const int c   = idx / F4PC;
        const int s4  = (idx % F4PC) << 2;
        if (idx < NV && s4 < valid) {
            v4f v = vbuf[k];
            if (c >= 4) {
                #pragma unroll
                for (int j = 0; j < 4; ++j)
                    v[j] = __builtin_amdgcn_rcpf(1.0f + __expf(-v[j]));  // sigmoid
            } else if (c == 0) {
                const int sp_ = s0 + s4;
                #pragma unroll
                for (int j = 0; j < 4; ++j) {
                    const float sg = __builtin_amdgcn_rcpf(1.0f + __expf(-v[j]));
                    v[j] = (sg + (float)((sp_ + j) % GDIM)) * 8.0f;
                }
            } else if (c == 1) {
                const int sp_ = s0 + s4;
                #pragma unroll
                for (int j = 0; j < 4; ++j) {
                    const float sg = __builtin_amdgcn_rcpf(1.0f + __expf(-v[j]));
                    v[j] = (sg + (float)((sp_ + j) / GDIM)) * 8.0f;
                }
            } else {  // c == 2 or 3
                const float an = (c == 2) ? aw : ah;
                #pragma unroll
                for (int j = 0; j < 4; ++j)
                    v[j] = __expf(v[j]) * an;
            }
            // scatter: addr stride 86 floats -> 4-way bank aliasing only (cheap)
            #pragma unroll
            for (int j = 0; j < 4; ++j)
                tile[(s4 + j) * NCH + c] = v[j];
        }
    }
    __syncthreads();

    // ---- phase 2: pure copy, LDS (linear b128, conflict-free) -> global NT ----
    v4f* outp = (v4f*)(out + ((size_t)b * (NANC * SP) + (size_t)a * SP + (size_t)s0) * NCH);
    const int nvalid = (valid * NCH) >> 2;   // 2752 or 344
    const v4f* lv = (const v4f*)tile;
    #pragma unroll
    for (int k = 0; k < 6; ++k) {
        const int v = tid + k * NT_;
        if (v < nvalid)
            __builtin_nontemporal_store(lv[v], outp + v);
    }
}

extern "C" void kernel_launch(void* const* d_in, const int* in_sizes, int n_in,
                              void* d_out, int out_size, void* d_ws, size_t ws_size,
                              hipStream_t stream) {
    const float* in = (const float*)d_in[0];
    float* out = (float*)d_out;
    const int B = in_sizes[0] / (NANC * NCH * SP);   // 32
    dim3 grid((SP + TS - 1) / TS, NANC, B);          // (46, 3, 32)
    yolo_decode_kernel<<<grid, NT_, 0, stream>>>(in, out);
}

// Round 3
// 317.789 us; speedup vs baseline: 1.0174x; 1.0138x over previous
//
#include <hip/hip_runtime.h>
#include <cstdint>

// YOLO head decode: [B, 3*86, 76, 76] fp32 -> [B, 3*76*76, 86] fp32
// c0: (sig(v)+i)*8, c1: (sig(v)+j)*8, c2: exp(v)*aw, c3: exp(v)*ah, c>=4: sig(v)
// (anchor/stride * stride cancels -> raw anchors)
//
// v4: IDENTICAL to v3 except nontemporal stores -> plain stores.
// Rationale: v1/v2/v3 (different LDS/compute/occupancy/segment structures) all
// land at 115-117us = 2.7 TB/s, while plain-store streams on this same chip
// (fillBuffer 6.56 TB/s, float4 copy 6.3 TB/s) run 2.4x faster. The NT write
// path is the only invariant shared by every variant. Single-variable test.

#define GDIM 76
#define SP   (GDIM * GDIM)   // 5776
#define NCH  86
#define NANC 3
#define TS   128             // spatial positions per tile
#define NT_  512             // threads per block
#define NV   (NCH * TS / 4)  // 2752 float4 per full tile
#define F4PC (TS / 4)        // 32 float4 per channel

typedef float v4f __attribute__((ext_vector_type(4)));

__global__ __launch_bounds__(NT_) void yolo_decode_kernel(
    const float* __restrict__ in, float* __restrict__ out) {
    // Output-layout staging: tile[s][c], unpadded & contiguous — byte-identical
    // to this block's output region. 44032 B -> 3 blocks/CU.
    __shared__ __align__(16) float tile[TS * NCH];

    const int tid   = threadIdx.x;
    const int chunk = blockIdx.x;        // 0..45
    const int a     = blockIdx.y;        // 0..2
    const int b     = blockIdx.z;        // 0..B-1
    const int s0    = chunk * TS;
    const int valid = min(TS, SP - s0);  // 128, or 16 tail (mult of 4)

    const float aw = (a == 0) ? 116.0f : (a == 1) ? 156.0f : 373.0f;
    const float ah = (a == 0) ?  90.0f : (a == 1) ? 198.0f : 326.0f;

    const float* inp = in + ((size_t)(b * (NANC * NCH) + a * NCH)) * SP + s0;

    // ---- phase 1a: issue all global loads (independent, coalesced float4) ----
    v4f vbuf[6];
    #pragma unroll
    for (int k = 0; k < 6; ++k) {
        const int idx = tid + k * NT_;
        const int c   = idx / F4PC;          // idx >> 5
        const int s4  = (idx % F4PC) << 2;
        if (idx < NV && s4 < valid)
            vbuf[k] = *(const v4f*)(inp + (size_t)c * SP + s4);
    }

    // ---- phase 1b: transform (thread-uniform channel) + scatter to LDS ----
    #pragma unroll
    for (int k = 0; k < 6; ++k) {
        const int idx = tid + k * NT_;
        const int c   = idx / F4PC;
        const int s4  = (idx % F4PC) << 2;
        if (idx < NV && s4 < valid) {
            v4f v = vbuf[k];
            if (c >= 4) {
                #pragma unroll
                for (int j = 0; j < 4; ++j)
                    v[j] = __builtin_amdgcn_rcpf(1.0f + __expf(-v[j]));  // sigmoid
            } else if (c == 0) {
                const int sp_ = s0 + s4;
                #pragma unroll
                for (int j = 0; j < 4; ++j) {
                    const float sg = __builtin_amdgcn_rcpf(1.0f + __expf(-v[j]));
                    v[j] = (sg + (float)((sp_ + j) % GDIM)) * 8.0f;
                }
            } else if (c == 1) {
                const int sp_ = s0 + s4;
                #pragma unroll
                for (int j = 0; j < 4; ++j) {
                    const float sg = __builtin_amdgcn_rcpf(1.0f + __expf(-v[j]));
                    v[j] = (sg + (float)((sp_ + j) / GDIM)) * 8.0f;
                }
            } else {  // c == 2 or 3
                const float an = (c == 2) ? aw : ah;
                #pragma unroll
                for (int j = 0; j < 4; ++j)
                    v[j] = __expf(v[j]) * an;
            }
            // scatter: addr stride 86 floats -> 4-way bank aliasing only (cheap)
            #pragma unroll
            for (int j = 0; j < 4; ++j)
                tile[(s4 + j) * NCH + c] = v[j];
        }
    }
    __syncthreads();

    // ---- phase 2: pure copy, LDS (linear b128, conflict-free) -> global ----
    v4f* outp = (v4f*)(out + ((size_t)b * (NANC * SP) + (size_t)a * SP + (size_t)s0) * NCH);
    const int nvalid = (valid * NCH) >> 2;   // 2752 or 344
    const v4f* lv = (const v4f*)tile;
    #pragma unroll
    for (int k = 0; k < 6; ++k) {
        const int v = tid + k * NT_;
        if (v < nvalid)
            outp[v] = lv[v];                 // plain store (NT removed)
    }
}

extern "C" void kernel_launch(void* const* d_in, const int* in_sizes, int n_in,
                              void* d_out, int out_size, void* d_ws, size_t ws_size,
                              hipStream_t stream) {
    const float* in = (const float*)d_in[0];
    float* out = (float*)d_out;
    const int B = in_sizes[0] / (NANC * NCH * SP);   // 32
    dim3 grid((SP + TS - 1) / TS, NANC, B);          // (46, 3, 32)
    yolo_decode_kernel<<<grid, NT_, 0, stream>>>(in, out);
}